// Round 4
// baseline (258.402 us; speedup 1.0000x reference)
//
#include <hip/hip_runtime.h>

// Batched Kalman predict: x_hat = Ap x ; P_hat = Ap P Ap^T + Q
// 8 threads per element (one P-row each); cross-row mixing via LDS.
// R4 = R3 with the nontemporal stores done through a native ext_vector_type
// (clang's builtin rejects HIP_vector_type<float,4>*).
//
// LDS: elem stride 100 dwords, row stride 12 dwords -> conflict-free reads
// (8-lane broadcast x 8 distinct bank starts) and writes.

#define ROW_STRIDE 12
#define ELEM_STRIDE 100
#define SLOTS 64          // 64 elements per block (2 chains x 32)

typedef float v4f __attribute__((ext_vector_type(4)));

__global__ __launch_bounds__(256) void kalman_predict_kernel(
    const float* __restrict__ x,
    const float* __restrict__ P,
    const float* __restrict__ A,
    const float* __restrict__ sigp_ptr,
    const float* __restrict__ sigv_ptr,
    float* __restrict__ x_hat,
    float* __restrict__ P_hat,
    int B)
{
    __shared__ float lds_m[SLOTS * ELEM_STRIDE];   // 25.6 KB

    // ---- Ap = triu(relu(A)), wave-uniform -> SGPRs ----
    float ap[64];
#pragma unroll
    for (int t = 0; t < 64; ++t) {
        float a = fmaxf(A[t], 0.0f);
        if ((t & 7) < (t >> 3)) a = 0.0f;   // triu
        ap[t] = __int_as_float(__builtin_amdgcn_readfirstlane(__float_as_int(a)));
    }
    float sigma_p = __int_as_float(__builtin_amdgcn_readfirstlane(__float_as_int(sigp_ptr[0])));
    float sigma_v = __int_as_float(__builtin_amdgcn_readfirstlane(__float_as_int(sigv_ptr[0])));

    int t = threadIdx.x;
    int r = t & 7;            // row within element
    int s = t >> 3;           // element slot 0..31
    size_t eb = (size_t)blockIdx.x * 64;
    size_t e0 = eb + s;
    size_t e1 = eb + s + 32;
    bool v0 = e0 < (size_t)B, v1 = e1 < (size_t)B;
    size_t c0 = v0 ? e0 : (size_t)(B - 1);
    size_t c1 = v1 ? e1 : (size_t)(B - 1);

    // ---- per-lane Ap row r ----
    const float4* arow = (const float4*)(A + r * 8);
    float4 a0 = arow[0], a1 = arow[1];
    float apr[8] = {a0.x, a0.y, a0.z, a0.w, a1.x, a1.y, a1.z, a1.w};
#pragma unroll
    for (int j = 0; j < 8; ++j) {
        float v = fmaxf(apr[j], 0.0f);
        apr[j] = (j >= r) ? v : 0.0f;
    }

    // ---- issue ALL global loads up front (both chains) ----
    const float4* pr0 = (const float4*)(P + c0 * 64 + r * 8);
    const float4* pr1 = (const float4*)(P + c1 * 64 + r * 8);
    float4 p0a = pr0[0], p0b = pr0[1];
    float4 p1a = pr1[0], p1b = pr1[1];
    const float4* xr0 = (const float4*)(x + c0 * 8);
    const float4* xr1 = (const float4*)(x + c1 * 8);
    float4 x0a = xr0[0], x0b = xr0[1];
    float4 x1a = xr1[0], x1b = xr1[1];

    float p0[8] = {p0a.x, p0a.y, p0a.z, p0a.w, p0b.x, p0b.y, p0b.z, p0b.w};
    float p1[8] = {p1a.x, p1a.y, p1a.z, p1a.w, p1b.x, p1b.y, p1b.z, p1b.w};
    float xv0[8] = {x0a.x, x0a.y, x0a.z, x0a.w, x0b.x, x0b.y, x0b.z, x0b.w};
    float xv1[8] = {x1a.x, x1a.y, x1a.z, x1a.w, x1b.x, x1b.y, x1b.z, x1b.w};

    // ---- step 1: M row r = P row r * Ap^T for both chains ----
    float m0[8], m1[8];
#pragma unroll
    for (int l = 0; l < 8; ++l) {
        float s0 = 0.0f, s1 = 0.0f;
#pragma unroll
        for (int k = 0; k < 8; ++k) {
            s0 = fmaf(ap[l * 8 + k], p0[k], s0);
            s1 = fmaf(ap[l * 8 + k], p1[k], s1);
        }
        m0[l] = s0; m1[l] = s1;
    }

    float* slot0 = lds_m + (s)      * ELEM_STRIDE + r * ROW_STRIDE;
    float* slot1 = lds_m + (s + 32) * ELEM_STRIDE + r * ROW_STRIDE;
    ((float4*)slot0)[0] = make_float4(m0[0], m0[1], m0[2], m0[3]);
    ((float4*)(slot0 + 4))[0] = make_float4(m0[4], m0[5], m0[6], m0[7]);
    ((float4*)slot1)[0] = make_float4(m1[0], m1[1], m1[2], m1[3]);
    ((float4*)(slot1 + 4))[0] = make_float4(m1[4], m1[5], m1[6], m1[7]);

    // ---- x_hat rows (store before barrier, nontemporal) ----
    float xh0 = 0.0f, xh1 = 0.0f;
#pragma unroll
    for (int j = 0; j < 8; ++j) {
        xh0 = fmaf(apr[j], xv0[j], xh0);
        xh1 = fmaf(apr[j], xv1[j], xh1);
    }
    if (v0) __builtin_nontemporal_store(xh0, x_hat + e0 * 8 + r);
    if (v1) __builtin_nontemporal_store(xh1, x_hat + e1 * 8 + r);

    // ---- Q diag entries ----
    float sig = (r < 4) ? sigma_p : sigma_v;
    float hv0 = (r & 1) ? xv0[3] : xv0[2];
    float hv1 = (r & 1) ? xv1[3] : xv1[2];
    float q0 = hv0 * sig; q0 *= q0;
    float q1 = hv1 * sig; q1 *= q1;

    __syncthreads();

    // ---- step 2: out[l] = sum_j apr[j] * M[j][l] (+ q at l==r) ----
    float out0[8], out1[8];
#pragma unroll
    for (int l = 0; l < 8; ++l) {
        out0[l] = (l == r) ? q0 : 0.0f;
        out1[l] = (l == r) ? q1 : 0.0f;
    }
    const float* eb0 = lds_m + (s)      * ELEM_STRIDE;
    const float* eb1 = lds_m + (s + 32) * ELEM_STRIDE;
#pragma unroll
    for (int j = 0; j < 8; ++j) {
        float4 ma = ((const float4*)(eb0 + j * ROW_STRIDE))[0];
        float4 mb = ((const float4*)(eb0 + j * ROW_STRIDE))[1];
        float aj = apr[j];
        out0[0] = fmaf(aj, ma.x, out0[0]); out0[1] = fmaf(aj, ma.y, out0[1]);
        out0[2] = fmaf(aj, ma.z, out0[2]); out0[3] = fmaf(aj, ma.w, out0[3]);
        out0[4] = fmaf(aj, mb.x, out0[4]); out0[5] = fmaf(aj, mb.y, out0[5]);
        out0[6] = fmaf(aj, mb.z, out0[6]); out0[7] = fmaf(aj, mb.w, out0[7]);
    }
#pragma unroll
    for (int j = 0; j < 8; ++j) {
        float4 ma = ((const float4*)(eb1 + j * ROW_STRIDE))[0];
        float4 mb = ((const float4*)(eb1 + j * ROW_STRIDE))[1];
        float aj = apr[j];
        out1[0] = fmaf(aj, ma.x, out1[0]); out1[1] = fmaf(aj, ma.y, out1[1]);
        out1[2] = fmaf(aj, ma.z, out1[2]); out1[3] = fmaf(aj, ma.w, out1[3]);
        out1[4] = fmaf(aj, mb.x, out1[4]); out1[5] = fmaf(aj, mb.y, out1[5]);
        out1[6] = fmaf(aj, mb.z, out1[6]); out1[7] = fmaf(aj, mb.w, out1[7]);
    }

    // ---- nontemporal coalesced stores via native vector type ----
    if (v0) {
        v4f* po = (v4f*)(P_hat + e0 * 64 + r * 8);
        v4f lo = {out0[0], out0[1], out0[2], out0[3]};
        v4f hi = {out0[4], out0[5], out0[6], out0[7]};
        __builtin_nontemporal_store(lo, po);
        __builtin_nontemporal_store(hi, po + 1);
    }
    if (v1) {
        v4f* po = (v4f*)(P_hat + e1 * 64 + r * 8);
        v4f lo = {out1[0], out1[1], out1[2], out1[3]};
        v4f hi = {out1[4], out1[5], out1[6], out1[7]};
        __builtin_nontemporal_store(lo, po);
        __builtin_nontemporal_store(hi, po + 1);
    }
}

extern "C" void kernel_launch(void* const* d_in, const int* in_sizes, int n_in,
                              void* d_out, int out_size, void* d_ws, size_t ws_size,
                              hipStream_t stream) {
    const float* x  = (const float*)d_in[0];
    const float* P  = (const float*)d_in[1];
    const float* A  = (const float*)d_in[2];
    const float* sp = (const float*)d_in[3];
    const float* sv = (const float*)d_in[4];

    int B = in_sizes[0] / 8;           // x is (B, 8, 1)
    float* x_hat = (float*)d_out;      // B*8 floats
    float* P_hat = (float*)d_out + (size_t)B * 8;  // B*64 floats

    int block = 256;
    int grid = (B + 63) / 64;          // 64 elements per block
    kalman_predict_kernel<<<grid, block, 0, stream>>>(x, P, A, sp, sv, x_hat, P_hat, B);
}